// Round 6
// baseline (1077.223 us; speedup 1.0000x reference)
//
#include <hip/hip_runtime.h>
#include <math.h>

#define NB 32768
#define EPS_REC 1e-4f

// Inter-stage staging (static device globals: graph-capture safe).
__device__ float g_x2[NB * 256];  // stage-1 output: B x 16 x 16
__device__ float g_x3[NB * 16];   // stage-2 output: B x 4 x 4

// Wave-synchronous "barrier": matrix groups live entirely inside one wave64,
// lanes run in lockstep, same-wave LDS ops complete in order. Only compiler
// reordering must be inhibited -> zero HW cost. (R3: per-round cost identical
// to s_barrier version; the win is structural, not the barrier itself.)
__device__ __forceinline__ void wsync() {
  asm volatile("" ::: "memory");
  __builtin_amdgcn_wave_barrier();
  asm volatile("" ::: "memory");
}

// Swap values between adjacent lanes (lane ^ 1) via DPP quad_perm [1,0,3,2].
// Pairs (2k,2k+1) are even-aligned so they never cross a quad. VALU-pipe op.
__device__ __forceinline__ float dpp_swap1(float x) {
  int xi = __builtin_bit_cast(int, x);
  int yi = __builtin_amdgcn_update_dpp(xi, xi, 0xB1, 0xF, 0xF, true);
  return __builtin_bit_cast(float, yi);
}

// Tournament (circle-method) slot permutation: content of slot s moves to
// permf(s). Over N-1 rounds with fixed pairing (2k,2k+1) every pair meets
// exactly once.
__host__ __device__ constexpr int permf(int s, int n) {
  return s == 0 ? 0
       : s == 2 ? 1
       : (s & 1) ? (s == n - 1 ? n - 2 : s + 2)
       : s - 2;
}

// Jacobi rotation (c,s) zeroing A[p][q]; G = [[c,s],[-s,c]].
__device__ __forceinline__ void rot_cs(float app, float aqq, float apq,
                                       float& c, float& s) {
  float dd = 0.5f * (app - aqq);
  float q2 = apq * apq;
  float hh = dd * dd + q2 + 1e-30f;
  float h = sqrtf(hh);
  float u = fabsf(dd) + h;
  float gi = rsqrtf(u * u + q2);
  c = u * gi;
  float smag = apq * gi;
  s = (dd >= 0.f) ? -smag : smag;
}

// One Jacobi round, static slot pairing (2k,2k+1), data permuted by permf.
// A in LDS chunk-major: SA4g[t*N + j] = rows 4t..4t+3 of column-slot j.
// U rows ping-pong through register arrays ua -> ub (static indices only).
// Partner-column row-phased values come via DPP, not LDS.
template <int N>
__device__ __forceinline__ void jround(float* SAf, float4* SA4g, float2* CSg,
                                       const float* ua, float* ub, int sub,
                                       int kpair, bool isP, int appAddr,
                                       int aqqAddr, int wcol) {
  constexpr int C = N / 4;
  float2 a01 = *(const float2*)(SAf + appAddr);  // app, apq (adjacent rows)
  float aqq = SAf[aqqAddr];
  float c, s;
  rot_cs(a01.x, aqq, a01.y, c, s);
  if (isP) CSg[kpair] = make_float2(c, s);
  float beta = isP ? -s : s;
  wsync();
  const float4* CS4 = (const float4*)CSg;
  float nn[N];
#pragma unroll
  for (int t = 0; t < C; ++t) {
    float4 cs = CS4[t];            // (c,s) of pairs 2t, 2t+1 (broadcast)
    float4 oc = SA4g[t * N + sub]; // own column, rows 4t..4t+3
    {  // pair 2t: rows p=4t, q=4t+1
      const int p = 4 * t, q = 4 * t + 1;
      float xr = cs.x * oc.x - cs.y * oc.y;
      float yr = cs.y * oc.x + cs.x * oc.y;
      nn[permf(p, N)] = c * xr + beta * dpp_swap1(xr);
      nn[permf(q, N)] = c * yr + beta * dpp_swap1(yr);
      float ux = ua[p], uy = ua[q];
      ub[permf(p, N)] = cs.x * ux - cs.y * uy;
      ub[permf(q, N)] = cs.y * ux + cs.x * uy;
    }
    {  // pair 2t+1: rows p=4t+2, q=4t+3
      const int p = 4 * t + 2, q = 4 * t + 3;
      float xr = cs.z * oc.z - cs.w * oc.w;
      float yr = cs.w * oc.z + cs.z * oc.w;
      nn[permf(p, N)] = c * xr + beta * dpp_swap1(xr);
      nn[permf(q, N)] = c * yr + beta * dpp_swap1(yr);
      float ux = ua[p], uy = ua[q];
      ub[permf(p, N)] = cs.z * ux - cs.w * uy;
      ub[permf(q, N)] = cs.w * ux + cs.z * uy;
    }
  }
  wsync();  // all reads of old columns precede any overwrite (lockstep)
#pragma unroll
  for (int t = 0; t < C; ++t)
    SA4g[t * N + wcol] =
        make_float4(nn[4 * t], nn[4 * t + 1], nn[4 * t + 2], nn[4 * t + 3]);
  wsync();
}

// iters must be even (ping-pong); final U rows end in ur.
template <int N>
__device__ __forceinline__ void jacobi_rr(float4* SA4g, float2* CSg, float* ur,
                                          float* un, int sub, int iters) {
  float* SAf = (float*)SA4g;
  const int kpair = sub >> 1;
  const bool isP = !(sub & 1);
  const int pp = sub & ~1;
  const int qq = pp + 1;
  const int appAddr = ((pp >> 2) * N + pp) * 4 + (pp & 3);
  const int aqqAddr = ((qq >> 2) * N + qq) * 4 + (qq & 3);
  const int wcol = permf(sub, N);
#pragma unroll 1
  for (int it = 0; it < iters; it += 2) {
    jround<N>(SAf, SA4g, CSg, ur, un, sub, kpair, isP, appAddr, aqqAddr, wcol);
    jround<N>(SAf, SA4g, CSg, un, ur, sub, kpair, isP, appAddr, aqqAddr, wcol);
  }
}

// Stage 1: X1 = w1^T X w1 (19 padded to 20), ReEig via Jacobi, then
// X2 = Y^T Lam Y with Y = U^T w2. 3 matrices per wave (lanes 60..63 idle ->
// shared dummy slot 6), 128-thread blocks = 6 matrices.
// launch_bounds(128,6): ~85-VGPR budget >= ~72 live -> no AGPR shuttle.
__global__ __launch_bounds__(128, 6) void spd_stage1(
    const float* __restrict__ x, const float* __restrict__ w1,
    const float* __restrict__ w2) {
  __shared__ float4 SA[7 * 100];  // 6 real groups + 1 dummy, 5 chunks x 20
  __shared__ float2 CS[7 * 10];
  __shared__ float SL[7 * 20];
  int tid = threadIdx.x;
  int wid = tid >> 6;
  int lane = tid & 63;
  int gl = lane / 20;  // 0..3 (3 = idle lanes 60..63)
  int sub = lane - gl * 20;
  bool lane_ok = (gl < 3);
  int g = lane_ok ? (wid * 3 + gl) : 6;
  int b = blockIdx.x * 6 + g;
  bool valid = lane_ok && (b < NB);
  int bm = valid ? b : 0;
  float4* SA4g = SA + g * 100;
  float* SAf = (float*)SA4g;
  float2* CSg = CS + g * 10;
  float* SLg = SL + g * 20;

  // ---- bilinear: Z = w1^T X (col sub), then X1 = Z w1 ----
  const float* xb = x + bm * 361;
  float cx[19];
#pragma unroll
  for (int i = 0; i < 19; ++i) cx[i] = (sub < 19) ? xb[i * 19 + sub] : 0.f;
  float z[20];
  z[19] = 0.f;
#pragma unroll
  for (int i = 0; i < 19; ++i) {
    float acc = 0.f;
#pragma unroll
    for (int r = 0; r < 19; ++r) acc += w1[r * 19 + i] * cx[r];
    z[i] = acc;
  }
#pragma unroll
  for (int t = 0; t < 5; ++t)
    SA4g[t * 20 + sub] =
        make_float4(z[4 * t], z[4 * t + 1], z[4 * t + 2], z[4 * t + 3]);
  wsync();
  float wj[19];
#pragma unroll
  for (int r = 0; r < 19; ++r) wj[r] = (sub < 19) ? w1[r * 19 + sub] : 0.f;
  float a1[20];
#pragma unroll
  for (int i = 0; i < 20; ++i) a1[i] = 0.f;
#pragma unroll
  for (int r = 0; r < 19; ++r) {
    float wr = wj[r];
#pragma unroll
    for (int t = 0; t < 5; ++t) {
      float4 zc = SA4g[t * 20 + r];  // Z rows 4t..4t+3, col r (broadcast)
      a1[4 * t + 0] += zc.x * wr;
      a1[4 * t + 1] += zc.y * wr;
      a1[4 * t + 2] += zc.z * wr;
      a1[4 * t + 3] += zc.w * wr;
    }
  }
  wsync();
  // padded A: col 19 = 0 (diag 0 -> clamped to eps; exact invariant subspace)
#pragma unroll
  for (int t = 0; t < 5; ++t)
    SA4g[t * 20 + sub] =
        make_float4(a1[4 * t], a1[4 * t + 1], a1[4 * t + 2], a1[4 * t + 3]);
  float ur[20], un[20];
#pragma unroll
  for (int i = 0; i < 20; ++i) ur[i] = (i == sub) ? 1.f : 0.f;
  wsync();

  jacobi_rr<20>(SA4g, CSg, ur, un, sub, 86);  // ~4.5 sweeps, even

  const int dAddr = ((sub >> 2) * 20 + sub) * 4 + (sub & 3);
  float lam = fmaxf(SAf[dAddr], EPS_REC);
  SLg[sub] = lam;
  wsync();
  // SA col sub <- U row sub  (=> SAf elem(i,j) = U[j][i])
#pragma unroll
  for (int t = 0; t < 5; ++t)
    SA4g[t * 20 + sub] =
        make_float4(ur[4 * t], ur[4 * t + 1], ur[4 * t + 2], ur[4 * t + 3]);
  wsync();
  // Y[r][sub] = sum_{i<19} U[i][r] * w2[i][sub]
  float wj2[19];
#pragma unroll
  for (int i = 0; i < 19; ++i) wj2[i] = (sub < 16) ? w2[i * 16 + sub] : 0.f;
  float y[20];
#pragma unroll
  for (int r = 0; r < 20; ++r) y[r] = 0.f;
#pragma unroll
  for (int i = 0; i < 19; ++i) {
    float wv = wj2[i];
#pragma unroll
    for (int t = 0; t < 5; ++t) {
      float4 u4 = SA4g[t * 20 + i];  // U[i][4t..4t+3] (broadcast)
      y[4 * t + 0] += u4.x * wv;
      y[4 * t + 1] += u4.y * wv;
      y[4 * t + 2] += u4.z * wv;
      y[4 * t + 3] += u4.w * wv;
    }
  }
  wsync();
#pragma unroll
  for (int t = 0; t < 5; ++t)
    SA4g[t * 20 + sub] =
        make_float4(y[4 * t], y[4 * t + 1], y[4 * t + 2], y[4 * t + 3]);
  wsync();
  float tr[20];
#pragma unroll
  for (int r = 0; r < 20; ++r) tr[r] = SLg[r] * y[r];
  if (valid && sub < 16) {
    float* outb = g_x2 + b * 256;
#pragma unroll
    for (int i = 0; i < 16; ++i) {
      float acc = 0.f;
#pragma unroll
      for (int t = 0; t < 5; ++t) {
        float4 yc = SA4g[t * 20 + i];  // Y rows 4t..4t+3, col i (broadcast)
        acc += yc.x * tr[4 * t] + yc.y * tr[4 * t + 1] + yc.z * tr[4 * t + 2] +
               yc.w * tr[4 * t + 3];
      }
      outb[i * 16 + sub] = acc;
    }
  }
}

// Stage 2: ReEig(16) via Jacobi, X3 = Y3^T Lam Y3 with Y3 = U^T w3 (16x4).
// 4 matrices per wave, 128-thread blocks = 8 matrices, all lanes active.
__global__ __launch_bounds__(128, 6) void spd_stage2(
    const float* __restrict__ w3) {
  __shared__ float4 SA[8 * 64];
  __shared__ float2 CS[8 * 8];
  __shared__ float SL[8 * 16];
  __shared__ float4 YL[8 * 16];
  int tid = threadIdx.x;
  int wid = tid >> 6;
  int lane = tid & 63;
  int gl = lane >> 4;
  int sub = lane & 15;
  int g = wid * 4 + gl;
  int b = blockIdx.x * 8 + g;
  float4* SA4g = SA + g * 64;
  float* SAf = (float*)SA4g;
  float2* CSg = CS + g * 8;
  float* SLg = SL + g * 16;
  float* YLf = (float*)(YL + g * 16);

  const float* xb = g_x2 + b * 256;
  float ca[16];
#pragma unroll
  for (int i = 0; i < 16; ++i) ca[i] = xb[i * 16 + sub];
#pragma unroll
  for (int t = 0; t < 4; ++t)
    SA4g[t * 16 + sub] =
        make_float4(ca[4 * t], ca[4 * t + 1], ca[4 * t + 2], ca[4 * t + 3]);
  float ur[16], un[16];
#pragma unroll
  for (int i = 0; i < 16; ++i) ur[i] = (i == sub) ? 1.f : 0.f;
  wsync();

  jacobi_rr<16>(SA4g, CSg, ur, un, sub, 60);  // 4 sweeps, even

  const int dAddr = ((sub >> 2) * 16 + sub) * 4 + (sub & 3);
  float lam = fmaxf(SAf[dAddr], EPS_REC);
  SLg[sub] = lam;
  wsync();
#pragma unroll
  for (int t = 0; t < 4; ++t)
    SA4g[t * 16 + sub] =
        make_float4(ur[4 * t], ur[4 * t + 1], ur[4 * t + 2], ur[4 * t + 3]);
  wsync();
  // Y3[sub][j] = sum_i U[i][sub]*w3[i][j]; U[i][sub] = SAf elem(sub,i)
  float y3[4] = {0.f, 0.f, 0.f, 0.f};
  const int rowBase = (sub >> 2) * 64 + (sub & 3);
#pragma unroll
  for (int i = 0; i < 16; ++i) {
    float u = SAf[rowBase + i * 4];
#pragma unroll
    for (int j = 0; j < 4; ++j) y3[j] += u * w3[i * 4 + j];
  }
  ((float4*)YLf)[sub] = make_float4(y3[0], y3[1], y3[2], y3[3]);
  wsync();
  int ii = sub >> 2, jj = sub & 3;
  float acc = 0.f;
#pragma unroll
  for (int r = 0; r < 16; ++r)
    acc += SLg[r] * YLf[r * 4 + ii] * YLf[r * 4 + jj];
  g_x3[b * 16 + sub] = acc;
}

// Stage 3: per-thread 4x4 LogEig in registers, FC(16->2), log_softmax.
__global__ __launch_bounds__(256) void spd_stage3(const float* __restrict__ fcw,
                                                  float* __restrict__ out) {
  int b = blockIdx.x * 256 + threadIdx.x;
  const float* xb = g_x3 + b * 16;
  float a[4][4];
#pragma unroll
  for (int i = 0; i < 4; ++i)
#pragma unroll
    for (int j = 0; j < 4; ++j) a[i][j] = xb[i * 4 + j];
  float vv[4][4];
#pragma unroll
  for (int i = 0; i < 4; ++i)
#pragma unroll
    for (int j = 0; j < 4; ++j) vv[i][j] = (i == j) ? 1.f : 0.f;

  constexpr int P4[6] = {0, 0, 0, 1, 1, 2};
  constexpr int Q4[6] = {1, 2, 3, 2, 3, 3};
  for (int sw = 0; sw < 6; ++sw) {
#pragma unroll
    for (int e = 0; e < 6; ++e) {
      const int p = P4[e], q = Q4[e];
      float c, s;
      rot_cs(a[p][p], a[q][q], a[p][q], c, s);
#pragma unroll
      for (int j = 0; j < 4; ++j) {
        float xx = a[p][j], yy = a[q][j];
        a[p][j] = c * xx - s * yy;
        a[q][j] = s * xx + c * yy;
      }
#pragma unroll
      for (int i = 0; i < 4; ++i) {
        float xx = a[i][p], yy = a[i][q];
        a[i][p] = c * xx - s * yy;
        a[i][q] = s * xx + c * yy;
      }
#pragma unroll
      for (int i = 0; i < 4; ++i) {
        float xx = vv[i][p], yy = vv[i][q];
        vv[i][p] = c * xx - s * yy;
        vv[i][q] = s * xx + c * yy;
      }
    }
  }
  float ll[4];
#pragma unroll
  for (int r = 0; r < 4; ++r) ll[r] = logf(fmaxf(a[r][r], 1e-12f));
  float feat[16];
#pragma unroll
  for (int i = 0; i < 4; ++i)
#pragma unroll
    for (int j = 0; j < 4; ++j) {
      float acc = 0.f;
#pragma unroll
      for (int r = 0; r < 4; ++r) acc += ll[r] * vv[i][r] * vv[j][r];
      feat[i * 4 + j] = acc;
    }
  float z0 = 0.f, z1 = 0.f;
#pragma unroll
  for (int k = 0; k < 16; ++k) {
    z0 += feat[k] * fcw[2 * k + 0];
    z1 += feat[k] * fcw[2 * k + 1];
  }
  float m = fmaxf(z0, z1);
  float lse = logf(expf(z0 - m) + expf(z1 - m));
  out[b * 2 + 0] = z0 - m - lse;
  out[b * 2 + 1] = z1 - m - lse;
#pragma unroll
  for (int k = 0; k < 16; ++k) out[2 * NB + b * 16 + k] = feat[k];
}

extern "C" void kernel_launch(void* const* d_in, const int* in_sizes, int n_in,
                              void* d_out, int out_size, void* d_ws,
                              size_t ws_size, hipStream_t stream) {
  (void)in_sizes;
  (void)n_in;
  (void)out_size;
  (void)d_ws;
  (void)ws_size;
  const float* x = (const float*)d_in[0];
  const float* w1 = (const float*)d_in[1];
  const float* w2 = (const float*)d_in[2];
  const float* w3 = (const float*)d_in[3];
  const float* fcw = (const float*)d_in[4];
  float* out = (float*)d_out;

  spd_stage1<<<(NB + 5) / 6, 128, 0, stream>>>(x, w1, w2);
  spd_stage2<<<NB / 8, 128, 0, stream>>>(w3);
  spd_stage3<<<NB / 256, 256, 0, stream>>>(fcw, out);
}

// Round 7
// 647.635 us; speedup vs baseline: 1.6633x; 1.6633x over previous
//
#include <hip/hip_runtime.h>
#include <math.h>

#define NB 32768
#define EPS_REC 1e-4f

// Inter-stage staging (static device globals: graph-capture safe).
__device__ float g_x2[NB * 256];  // stage-1 output: B x 16 x 16
__device__ float g_x3[NB * 16];   // stage-2 output: B x 4 x 4

// Wave-synchronous "barrier": matrix groups live entirely inside one wave64,
// lanes run in lockstep, same-wave LDS ops complete in order. Only compiler
// reordering must be inhibited -> zero HW cost.
// HISTORY (do not regress):
//  R5: dual-chain ILP (2 matrices/lane-group) -> occupancy halved, +22% time.
//  R6: __launch_bounds__(128,6) -> scratch spills (FETCH 23->407MB), +60%.
//  (128,4) is the validated register/occupancy local optimum.
__device__ __forceinline__ void wsync() {
  asm volatile("" ::: "memory");
  __builtin_amdgcn_wave_barrier();
  asm volatile("" ::: "memory");
}

// Swap values between adjacent lanes (lane ^ 1) via DPP quad_perm [1,0,3,2].
// Pairs (2k,2k+1) are even-aligned so they never cross a quad. VALU-pipe op.
__device__ __forceinline__ float dpp_swap1(float x) {
  int xi = __builtin_bit_cast(int, x);
  int yi = __builtin_amdgcn_update_dpp(xi, xi, 0xB1, 0xF, 0xF, true);
  return __builtin_bit_cast(float, yi);
}

// Tournament (circle-method) slot permutation: content of slot s moves to
// permf(s). Over N-1 rounds with fixed pairing (2k,2k+1) every pair meets
// exactly once.
__host__ __device__ constexpr int permf(int s, int n) {
  return s == 0 ? 0
       : s == 2 ? 1
       : (s & 1) ? (s == n - 1 ? n - 2 : s + 2)
       : s - 2;
}

// Jacobi rotation (c,s) zeroing A[p][q]; G = [[c,s],[-s,c]].
__device__ __forceinline__ void rot_cs(float app, float aqq, float apq,
                                       float& c, float& s) {
  float dd = 0.5f * (app - aqq);
  float q2 = apq * apq;
  float hh = dd * dd + q2 + 1e-30f;
  float h = sqrtf(hh);
  float u = fabsf(dd) + h;
  float gi = rsqrtf(u * u + q2);
  c = u * gi;
  float smag = apq * gi;
  s = (dd >= 0.f) ? -smag : smag;
}

// One Jacobi round, static slot pairing (2k,2k+1), data permuted by permf.
// A in LDS chunk-major: SA4g[t*N + j] = rows 4t..4t+3 of column-slot j.
// U rows ping-pong through register arrays ua -> ub (static indices only).
// Partner-column row-phased values come via DPP, not LDS.
template <int N>
__device__ __forceinline__ void jround(float* SAf, float4* SA4g, float2* CSg,
                                       const float* ua, float* ub, int sub,
                                       int kpair, bool isP, int appAddr,
                                       int aqqAddr, int wcol) {
  constexpr int C = N / 4;
  float2 a01 = *(const float2*)(SAf + appAddr);  // app, apq (adjacent rows)
  float aqq = SAf[aqqAddr];
  float c, s;
  rot_cs(a01.x, aqq, a01.y, c, s);
  if (isP) CSg[kpair] = make_float2(c, s);
  float beta = isP ? -s : s;
  wsync();
  const float4* CS4 = (const float4*)CSg;
  float nn[N];
#pragma unroll
  for (int t = 0; t < C; ++t) {
    float4 cs = CS4[t];            // (c,s) of pairs 2t, 2t+1 (broadcast)
    float4 oc = SA4g[t * N + sub]; // own column, rows 4t..4t+3
    {  // pair 2t: rows p=4t, q=4t+1
      const int p = 4 * t, q = 4 * t + 1;
      float xr = cs.x * oc.x - cs.y * oc.y;
      float yr = cs.y * oc.x + cs.x * oc.y;
      nn[permf(p, N)] = c * xr + beta * dpp_swap1(xr);
      nn[permf(q, N)] = c * yr + beta * dpp_swap1(yr);
      float ux = ua[p], uy = ua[q];
      ub[permf(p, N)] = cs.x * ux - cs.y * uy;
      ub[permf(q, N)] = cs.y * ux + cs.x * uy;
    }
    {  // pair 2t+1: rows p=4t+2, q=4t+3
      const int p = 4 * t + 2, q = 4 * t + 3;
      float xr = cs.z * oc.z - cs.w * oc.w;
      float yr = cs.w * oc.z + cs.z * oc.w;
      nn[permf(p, N)] = c * xr + beta * dpp_swap1(xr);
      nn[permf(q, N)] = c * yr + beta * dpp_swap1(yr);
      float ux = ua[p], uy = ua[q];
      ub[permf(p, N)] = cs.z * ux - cs.w * uy;
      ub[permf(q, N)] = cs.w * ux + cs.z * uy;
    }
  }
  wsync();  // all reads of old columns precede any overwrite (lockstep)
#pragma unroll
  for (int t = 0; t < C; ++t)
    SA4g[t * N + wcol] =
        make_float4(nn[4 * t], nn[4 * t + 1], nn[4 * t + 2], nn[4 * t + 3]);
  wsync();
}

// iters must be even (ping-pong); final U rows end in ur.
template <int N>
__device__ __forceinline__ void jacobi_rr(float4* SA4g, float2* CSg, float* ur,
                                          float* un, int sub, int iters) {
  float* SAf = (float*)SA4g;
  const int kpair = sub >> 1;
  const bool isP = !(sub & 1);
  const int pp = sub & ~1;
  const int qq = pp + 1;
  const int appAddr = ((pp >> 2) * N + pp) * 4 + (pp & 3);
  const int aqqAddr = ((qq >> 2) * N + qq) * 4 + (qq & 3);
  const int wcol = permf(sub, N);
#pragma unroll 1
  for (int it = 0; it < iters; it += 2) {
    jround<N>(SAf, SA4g, CSg, ur, un, sub, kpair, isP, appAddr, aqqAddr, wcol);
    jround<N>(SAf, SA4g, CSg, un, ur, sub, kpair, isP, appAddr, aqqAddr, wcol);
  }
}

// Stage 1: X1 = w1^T X w1 (19 padded to 20), ReEig via Jacobi, then
// X2 = Y^T Lam Y with Y = U^T w2. 3 matrices per wave (lanes 60..63 idle ->
// shared dummy slot 6), 128-thread blocks = 6 matrices.
__global__ __launch_bounds__(128, 4) void spd_stage1(
    const float* __restrict__ x, const float* __restrict__ w1,
    const float* __restrict__ w2) {
  __shared__ float4 SA[7 * 100];  // 6 real groups + 1 dummy, 5 chunks x 20
  __shared__ float2 CS[7 * 10];
  __shared__ float SL[7 * 20];
  int tid = threadIdx.x;
  int wid = tid >> 6;
  int lane = tid & 63;
  int gl = lane / 20;  // 0..3 (3 = idle lanes 60..63)
  int sub = lane - gl * 20;
  bool lane_ok = (gl < 3);
  int g = lane_ok ? (wid * 3 + gl) : 6;
  int b = blockIdx.x * 6 + g;
  bool valid = lane_ok && (b < NB);
  int bm = valid ? b : 0;
  float4* SA4g = SA + g * 100;
  float* SAf = (float*)SA4g;
  float2* CSg = CS + g * 10;
  float* SLg = SL + g * 20;

  // ---- bilinear: Z = w1^T X (col sub), then X1 = Z w1 ----
  const float* xb = x + bm * 361;
  float cx[19];
#pragma unroll
  for (int i = 0; i < 19; ++i) cx[i] = (sub < 19) ? xb[i * 19 + sub] : 0.f;
  float z[20];
  z[19] = 0.f;
#pragma unroll
  for (int i = 0; i < 19; ++i) {
    float acc = 0.f;
#pragma unroll
    for (int r = 0; r < 19; ++r) acc += w1[r * 19 + i] * cx[r];
    z[i] = acc;
  }
#pragma unroll
  for (int t = 0; t < 5; ++t)
    SA4g[t * 20 + sub] =
        make_float4(z[4 * t], z[4 * t + 1], z[4 * t + 2], z[4 * t + 3]);
  wsync();
  float wj[19];
#pragma unroll
  for (int r = 0; r < 19; ++r) wj[r] = (sub < 19) ? w1[r * 19 + sub] : 0.f;
  float a1[20];
#pragma unroll
  for (int i = 0; i < 20; ++i) a1[i] = 0.f;
#pragma unroll
  for (int r = 0; r < 19; ++r) {
    float wr = wj[r];
#pragma unroll
    for (int t = 0; t < 5; ++t) {
      float4 zc = SA4g[t * 20 + r];  // Z rows 4t..4t+3, col r (broadcast)
      a1[4 * t + 0] += zc.x * wr;
      a1[4 * t + 1] += zc.y * wr;
      a1[4 * t + 2] += zc.z * wr;
      a1[4 * t + 3] += zc.w * wr;
    }
  }
  wsync();
  // padded A: col 19 = 0 (diag 0 -> clamped to eps; exact invariant subspace)
#pragma unroll
  for (int t = 0; t < 5; ++t)
    SA4g[t * 20 + sub] =
        make_float4(a1[4 * t], a1[4 * t + 1], a1[4 * t + 2], a1[4 * t + 3]);
  float ur[20], un[20];
#pragma unroll
  for (int i = 0; i < 20; ++i) ur[i] = (i == sub) ? 1.f : 0.f;
  wsync();

  jacobi_rr<20>(SA4g, CSg, ur, un, sub, 76);  // 4 sweeps (abs-err plateau)

  const int dAddr = ((sub >> 2) * 20 + sub) * 4 + (sub & 3);
  float lam = fmaxf(SAf[dAddr], EPS_REC);
  SLg[sub] = lam;
  wsync();
  // SA col sub <- U row sub  (=> SAf elem(i,j) = U[j][i])
#pragma unroll
  for (int t = 0; t < 5; ++t)
    SA4g[t * 20 + sub] =
        make_float4(ur[4 * t], ur[4 * t + 1], ur[4 * t + 2], ur[4 * t + 3]);
  wsync();
  // Y[r][sub] = sum_{i<19} U[i][r] * w2[i][sub]
  float wj2[19];
#pragma unroll
  for (int i = 0; i < 19; ++i) wj2[i] = (sub < 16) ? w2[i * 16 + sub] : 0.f;
  float y[20];
#pragma unroll
  for (int r = 0; r < 20; ++r) y[r] = 0.f;
#pragma unroll
  for (int i = 0; i < 19; ++i) {
    float wv = wj2[i];
#pragma unroll
    for (int t = 0; t < 5; ++t) {
      float4 u4 = SA4g[t * 20 + i];  // U[i][4t..4t+3] (broadcast)
      y[4 * t + 0] += u4.x * wv;
      y[4 * t + 1] += u4.y * wv;
      y[4 * t + 2] += u4.z * wv;
      y[4 * t + 3] += u4.w * wv;
    }
  }
  wsync();
#pragma unroll
  for (int t = 0; t < 5; ++t)
    SA4g[t * 20 + sub] =
        make_float4(y[4 * t], y[4 * t + 1], y[4 * t + 2], y[4 * t + 3]);
  wsync();
  float tr[20];
#pragma unroll
  for (int r = 0; r < 20; ++r) tr[r] = SLg[r] * y[r];
  if (valid && sub < 16) {
    float* outb = g_x2 + b * 256;
#pragma unroll
    for (int i = 0; i < 16; ++i) {
      float acc = 0.f;
#pragma unroll
      for (int t = 0; t < 5; ++t) {
        float4 yc = SA4g[t * 20 + i];  // Y rows 4t..4t+3, col i (broadcast)
        acc += yc.x * tr[4 * t] + yc.y * tr[4 * t + 1] + yc.z * tr[4 * t + 2] +
               yc.w * tr[4 * t + 3];
      }
      outb[i * 16 + sub] = acc;
    }
  }
}

// Stage 2: ReEig(16) via Jacobi, X3 = Y3^T Lam Y3 with Y3 = U^T w3 (16x4).
// 4 matrices per wave, 128-thread blocks = 8 matrices, all lanes active.
__global__ __launch_bounds__(128, 4) void spd_stage2(
    const float* __restrict__ w3) {
  __shared__ float4 SA[8 * 64];
  __shared__ float2 CS[8 * 8];
  __shared__ float SL[8 * 16];
  __shared__ float4 YL[8 * 16];
  int tid = threadIdx.x;
  int wid = tid >> 6;
  int lane = tid & 63;
  int gl = lane >> 4;
  int sub = lane & 15;
  int g = wid * 4 + gl;
  int b = blockIdx.x * 8 + g;
  float4* SA4g = SA + g * 64;
  float* SAf = (float*)SA4g;
  float2* CSg = CS + g * 8;
  float* SLg = SL + g * 16;
  float* YLf = (float*)(YL + g * 16);

  const float* xb = g_x2 + b * 256;
  float ca[16];
#pragma unroll
  for (int i = 0; i < 16; ++i) ca[i] = xb[i * 16 + sub];
#pragma unroll
  for (int t = 0; t < 4; ++t)
    SA4g[t * 16 + sub] =
        make_float4(ca[4 * t], ca[4 * t + 1], ca[4 * t + 2], ca[4 * t + 3]);
  float ur[16], un[16];
#pragma unroll
  for (int i = 0; i < 16; ++i) ur[i] = (i == sub) ? 1.f : 0.f;
  wsync();

  jacobi_rr<16>(SA4g, CSg, ur, un, sub, 60);  // 4 sweeps

  const int dAddr = ((sub >> 2) * 16 + sub) * 4 + (sub & 3);
  float lam = fmaxf(SAf[dAddr], EPS_REC);
  SLg[sub] = lam;
  wsync();
#pragma unroll
  for (int t = 0; t < 4; ++t)
    SA4g[t * 16 + sub] =
        make_float4(ur[4 * t], ur[4 * t + 1], ur[4 * t + 2], ur[4 * t + 3]);
  wsync();
  // Y3[sub][j] = sum_i U[i][sub]*w3[i][j]; U[i][sub] = SAf elem(sub,i)
  float y3[4] = {0.f, 0.f, 0.f, 0.f};
  const int rowBase = (sub >> 2) * 64 + (sub & 3);
#pragma unroll
  for (int i = 0; i < 16; ++i) {
    float u = SAf[rowBase + i * 4];
#pragma unroll
    for (int j = 0; j < 4; ++j) y3[j] += u * w3[i * 4 + j];
  }
  ((float4*)YLf)[sub] = make_float4(y3[0], y3[1], y3[2], y3[3]);
  wsync();
  int ii = sub >> 2, jj = sub & 3;
  float acc = 0.f;
#pragma unroll
  for (int r = 0; r < 16; ++r)
    acc += SLg[r] * YLf[r * 4 + ii] * YLf[r * 4 + jj];
  g_x3[b * 16 + sub] = acc;
}

// Stage 3: per-thread 4x4 LogEig in registers, FC(16->2), log_softmax.
__global__ __launch_bounds__(256) void spd_stage3(const float* __restrict__ fcw,
                                                  float* __restrict__ out) {
  int b = blockIdx.x * 256 + threadIdx.x;
  const float* xb = g_x3 + b * 16;
  float a[4][4];
#pragma unroll
  for (int i = 0; i < 4; ++i)
#pragma unroll
    for (int j = 0; j < 4; ++j) a[i][j] = xb[i * 4 + j];
  float vv[4][4];
#pragma unroll
  for (int i = 0; i < 4; ++i)
#pragma unroll
    for (int j = 0; j < 4; ++j) vv[i][j] = (i == j) ? 1.f : 0.f;

  constexpr int P4[6] = {0, 0, 0, 1, 1, 2};
  constexpr int Q4[6] = {1, 2, 3, 2, 3, 3};
  for (int sw = 0; sw < 6; ++sw) {
#pragma unroll
    for (int e = 0; e < 6; ++e) {
      const int p = P4[e], q = Q4[e];
      float c, s;
      rot_cs(a[p][p], a[q][q], a[p][q], c, s);
#pragma unroll
      for (int j = 0; j < 4; ++j) {
        float xx = a[p][j], yy = a[q][j];
        a[p][j] = c * xx - s * yy;
        a[q][j] = s * xx + c * yy;
      }
#pragma unroll
      for (int i = 0; i < 4; ++i) {
        float xx = a[i][p], yy = a[i][q];
        a[i][p] = c * xx - s * yy;
        a[i][q] = s * xx + c * yy;
      }
#pragma unroll
      for (int i = 0; i < 4; ++i) {
        float xx = vv[i][p], yy = vv[i][q];
        vv[i][p] = c * xx - s * yy;
        vv[i][q] = s * xx + c * yy;
      }
    }
  }
  float ll[4];
#pragma unroll
  for (int r = 0; r < 4; ++r) ll[r] = logf(fmaxf(a[r][r], 1e-12f));
  float feat[16];
#pragma unroll
  for (int i = 0; i < 4; ++i)
#pragma unroll
    for (int j = 0; j < 4; ++j) {
      float acc = 0.f;
#pragma unroll
      for (int r = 0; r < 4; ++r) acc += ll[r] * vv[i][r] * vv[j][r];
      feat[i * 4 + j] = acc;
    }
  float z0 = 0.f, z1 = 0.f;
#pragma unroll
  for (int k = 0; k < 16; ++k) {
    z0 += feat[k] * fcw[2 * k + 0];
    z1 += feat[k] * fcw[2 * k + 1];
  }
  float m = fmaxf(z0, z1);
  float lse = logf(expf(z0 - m) + expf(z1 - m));
  out[b * 2 + 0] = z0 - m - lse;
  out[b * 2 + 1] = z1 - m - lse;
#pragma unroll
  for (int k = 0; k < 16; ++k) out[2 * NB + b * 16 + k] = feat[k];
}

extern "C" void kernel_launch(void* const* d_in, const int* in_sizes, int n_in,
                              void* d_out, int out_size, void* d_ws,
                              size_t ws_size, hipStream_t stream) {
  (void)in_sizes;
  (void)n_in;
  (void)out_size;
  (void)d_ws;
  (void)ws_size;
  const float* x = (const float*)d_in[0];
  const float* w1 = (const float*)d_in[1];
  const float* w2 = (const float*)d_in[2];
  const float* w3 = (const float*)d_in[3];
  const float* fcw = (const float*)d_in[4];
  float* out = (float*)d_out;

  spd_stage1<<<(NB + 5) / 6, 128, 0, stream>>>(x, w1, w2);
  spd_stage2<<<NB / 8, 128, 0, stream>>>(w3);
  spd_stage3<<<NB / 256, 256, 0, stream>>>(fcw, out);
}

// Round 9
// 641.116 us; speedup vs baseline: 1.6802x; 1.0102x over previous
//
#include <hip/hip_runtime.h>
#include <math.h>

#define NB 32768
#define EPS_REC 1e-4f

// Inter-stage staging (static device globals: graph-capture safe).
__device__ float g_x2[NB * 256];  // stage-1 output: B x 16 x 16
__device__ float g_x3[NB * 16];   // stage-2 output: B x 4 x 4

// Wave-synchronous "barrier": matrix groups live entirely inside one wave64,
// lanes run in lockstep, same-wave LDS ops complete in order. Only compiler
// reordering must be inhibited -> zero HW cost.
// HISTORY (do not regress):
//  R5: dual-chain ILP (2 matrices/lane-group) -> occupancy halved, +22% time.
//  R6: __launch_bounds__(128,6) -> scratch spills (FETCH 23->407MB), +60%.
//  R8: 3 sweeps -> absmax 1.375 > 0.69 FAIL. 4 sweeps is the minimum
//      (7->0.125, 5->0.25, 4->0.25, 3->1.375; plateau = fp32 noise floor).
//  (128,4) + 4 sweeps is the validated optimum (~12.4 waves/CU, capped by
//  unified VGPR+AGPR ~160/wave; latency-bound, DS ~58%, VALU ~40%/SIMD).
__device__ __forceinline__ void wsync() {
  asm volatile("" ::: "memory");
  __builtin_amdgcn_wave_barrier();
  asm volatile("" ::: "memory");
}

// Swap values between adjacent lanes (lane ^ 1) via DPP quad_perm [1,0,3,2].
// Pairs (2k,2k+1) are even-aligned so they never cross a quad. VALU-pipe op.
__device__ __forceinline__ float dpp_swap1(float x) {
  int xi = __builtin_bit_cast(int, x);
  int yi = __builtin_amdgcn_update_dpp(xi, xi, 0xB1, 0xF, 0xF, true);
  return __builtin_bit_cast(float, yi);
}

// Tournament (circle-method) slot permutation: content of slot s moves to
// permf(s). Over N-1 rounds with fixed pairing (2k,2k+1) every pair meets
// exactly once.
__host__ __device__ constexpr int permf(int s, int n) {
  return s == 0 ? 0
       : s == 2 ? 1
       : (s & 1) ? (s == n - 1 ? n - 2 : s + 2)
       : s - 2;
}

// Jacobi rotation (c,s) zeroing A[p][q]; G = [[c,s],[-s,c]].
__device__ __forceinline__ void rot_cs(float app, float aqq, float apq,
                                       float& c, float& s) {
  float dd = 0.5f * (app - aqq);
  float q2 = apq * apq;
  float hh = dd * dd + q2 + 1e-30f;
  float h = sqrtf(hh);
  float u = fabsf(dd) + h;
  float gi = rsqrtf(u * u + q2);
  c = u * gi;
  float smag = apq * gi;
  s = (dd >= 0.f) ? -smag : smag;
}

// One Jacobi round, static slot pairing (2k,2k+1), data permuted by permf.
// A in LDS chunk-major: SA4g[t*N + j] = rows 4t..4t+3 of column-slot j.
// U rows ping-pong through register arrays ua -> ub (static indices only).
// Partner-column row-phased values come via DPP, not LDS.
template <int N>
__device__ __forceinline__ void jround(float* SAf, float4* SA4g, float2* CSg,
                                       const float* ua, float* ub, int sub,
                                       int kpair, bool isP, int appAddr,
                                       int aqqAddr, int wcol) {
  constexpr int C = N / 4;
  float2 a01 = *(const float2*)(SAf + appAddr);  // app, apq (adjacent rows)
  float aqq = SAf[aqqAddr];
  float c, s;
  rot_cs(a01.x, aqq, a01.y, c, s);
  if (isP) CSg[kpair] = make_float2(c, s);
  float beta = isP ? -s : s;
  wsync();
  const float4* CS4 = (const float4*)CSg;
  float nn[N];
#pragma unroll
  for (int t = 0; t < C; ++t) {
    float4 cs = CS4[t];            // (c,s) of pairs 2t, 2t+1 (broadcast)
    float4 oc = SA4g[t * N + sub]; // own column, rows 4t..4t+3
    {  // pair 2t: rows p=4t, q=4t+1
      const int p = 4 * t, q = 4 * t + 1;
      float xr = cs.x * oc.x - cs.y * oc.y;
      float yr = cs.y * oc.x + cs.x * oc.y;
      nn[permf(p, N)] = c * xr + beta * dpp_swap1(xr);
      nn[permf(q, N)] = c * yr + beta * dpp_swap1(yr);
      float ux = ua[p], uy = ua[q];
      ub[permf(p, N)] = cs.x * ux - cs.y * uy;
      ub[permf(q, N)] = cs.y * ux + cs.x * uy;
    }
    {  // pair 2t+1: rows p=4t+2, q=4t+3
      const int p = 4 * t + 2, q = 4 * t + 3;
      float xr = cs.z * oc.z - cs.w * oc.w;
      float yr = cs.w * oc.z + cs.z * oc.w;
      nn[permf(p, N)] = c * xr + beta * dpp_swap1(xr);
      nn[permf(q, N)] = c * yr + beta * dpp_swap1(yr);
      float ux = ua[p], uy = ua[q];
      ub[permf(p, N)] = cs.z * ux - cs.w * uy;
      ub[permf(q, N)] = cs.w * ux + cs.z * uy;
    }
  }
  wsync();  // all reads of old columns precede any overwrite (lockstep)
#pragma unroll
  for (int t = 0; t < C; ++t)
    SA4g[t * N + wcol] =
        make_float4(nn[4 * t], nn[4 * t + 1], nn[4 * t + 2], nn[4 * t + 3]);
  wsync();
}

// iters must be even (ping-pong); final U rows end in ur.
template <int N>
__device__ __forceinline__ void jacobi_rr(float4* SA4g, float2* CSg, float* ur,
                                          float* un, int sub, int iters) {
  float* SAf = (float*)SA4g;
  const int kpair = sub >> 1;
  const bool isP = !(sub & 1);
  const int pp = sub & ~1;
  const int qq = pp + 1;
  const int appAddr = ((pp >> 2) * N + pp) * 4 + (pp & 3);
  const int aqqAddr = ((qq >> 2) * N + qq) * 4 + (qq & 3);
  const int wcol = permf(sub, N);
#pragma unroll 1
  for (int it = 0; it < iters; it += 2) {
    jround<N>(SAf, SA4g, CSg, ur, un, sub, kpair, isP, appAddr, aqqAddr, wcol);
    jround<N>(SAf, SA4g, CSg, un, ur, sub, kpair, isP, appAddr, aqqAddr, wcol);
  }
}

// Stage 1: X1 = w1^T X w1 (19 padded to 20), ReEig via Jacobi, then
// X2 = Y^T Lam Y with Y = U^T w2. 3 matrices per wave (lanes 60..63 idle ->
// shared dummy slot 6), 128-thread blocks = 6 matrices.
__global__ __launch_bounds__(128, 4) void spd_stage1(
    const float* __restrict__ x, const float* __restrict__ w1,
    const float* __restrict__ w2) {
  __shared__ float4 SA[7 * 100];  // 6 real groups + 1 dummy, 5 chunks x 20
  __shared__ float2 CS[7 * 10];
  __shared__ float SL[7 * 20];
  int tid = threadIdx.x;
  int wid = tid >> 6;
  int lane = tid & 63;
  int gl = lane / 20;  // 0..3 (3 = idle lanes 60..63)
  int sub = lane - gl * 20;
  bool lane_ok = (gl < 3);
  int g = lane_ok ? (wid * 3 + gl) : 6;
  int b = blockIdx.x * 6 + g;
  bool valid = lane_ok && (b < NB);
  int bm = valid ? b : 0;
  float4* SA4g = SA + g * 100;
  float* SAf = (float*)SA4g;
  float2* CSg = CS + g * 10;
  float* SLg = SL + g * 20;

  // ---- bilinear: Z = w1^T X (col sub), then X1 = Z w1 ----
  const float* xb = x + bm * 361;
  float cx[19];
#pragma unroll
  for (int i = 0; i < 19; ++i) cx[i] = (sub < 19) ? xb[i * 19 + sub] : 0.f;
  float z[20];
  z[19] = 0.f;
#pragma unroll
  for (int i = 0; i < 19; ++i) {
    float acc = 0.f;
#pragma unroll
    for (int r = 0; r < 19; ++r) acc += w1[r * 19 + i] * cx[r];
    z[i] = acc;
  }
#pragma unroll
  for (int t = 0; t < 5; ++t)
    SA4g[t * 20 + sub] =
        make_float4(z[4 * t], z[4 * t + 1], z[4 * t + 2], z[4 * t + 3]);
  wsync();
  float wj[19];
#pragma unroll
  for (int r = 0; r < 19; ++r) wj[r] = (sub < 19) ? w1[r * 19 + sub] : 0.f;
  float a1[20];
#pragma unroll
  for (int i = 0; i < 20; ++i) a1[i] = 0.f;
#pragma unroll
  for (int r = 0; r < 19; ++r) {
    float wr = wj[r];
#pragma unroll
    for (int t = 0; t < 5; ++t) {
      float4 zc = SA4g[t * 20 + r];  // Z rows 4t..4t+3, col r (broadcast)
      a1[4 * t + 0] += zc.x * wr;
      a1[4 * t + 1] += zc.y * wr;
      a1[4 * t + 2] += zc.z * wr;
      a1[4 * t + 3] += zc.w * wr;
    }
  }
  wsync();
  // padded A: col 19 = 0 (diag 0 -> clamped to eps; exact invariant subspace)
#pragma unroll
  for (int t = 0; t < 5; ++t)
    SA4g[t * 20 + sub] =
        make_float4(a1[4 * t], a1[4 * t + 1], a1[4 * t + 2], a1[4 * t + 3]);
  float ur[20], un[20];
#pragma unroll
  for (int i = 0; i < 20; ++i) ur[i] = (i == sub) ? 1.f : 0.f;
  wsync();

  jacobi_rr<20>(SA4g, CSg, ur, un, sub, 76);  // 4 sweeps (validated minimum)

  const int dAddr = ((sub >> 2) * 20 + sub) * 4 + (sub & 3);
  float lam = fmaxf(SAf[dAddr], EPS_REC);
  SLg[sub] = lam;
  wsync();
  // SA col sub <- U row sub  (=> SAf elem(i,j) = U[j][i])
#pragma unroll
  for (int t = 0; t < 5; ++t)
    SA4g[t * 20 + sub] =
        make_float4(ur[4 * t], ur[4 * t + 1], ur[4 * t + 2], ur[4 * t + 3]);
  wsync();
  // Y[r][sub] = sum_{i<19} U[i][r] * w2[i][sub]
  float wj2[19];
#pragma unroll
  for (int i = 0; i < 19; ++i) wj2[i] = (sub < 16) ? w2[i * 16 + sub] : 0.f;
  float y[20];
#pragma unroll
  for (int r = 0; r < 20; ++r) y[r] = 0.f;
#pragma unroll
  for (int i = 0; i < 19; ++i) {
    float wv = wj2[i];
#pragma unroll
    for (int t = 0; t < 5; ++t) {
      float4 u4 = SA4g[t * 20 + i];  // U[i][4t..4t+3] (broadcast)
      y[4 * t + 0] += u4.x * wv;
      y[4 * t + 1] += u4.y * wv;
      y[4 * t + 2] += u4.z * wv;
      y[4 * t + 3] += u4.w * wv;
    }
  }
  wsync();
#pragma unroll
  for (int t = 0; t < 5; ++t)
    SA4g[t * 20 + sub] =
        make_float4(y[4 * t], y[4 * t + 1], y[4 * t + 2], y[4 * t + 3]);
  wsync();
  float tr[20];
#pragma unroll
  for (int r = 0; r < 20; ++r) tr[r] = SLg[r] * y[r];
  if (valid && sub < 16) {
    float* outb = g_x2 + b * 256;
#pragma unroll
    for (int i = 0; i < 16; ++i) {
      float acc = 0.f;
#pragma unroll
      for (int t = 0; t < 5; ++t) {
        float4 yc = SA4g[t * 20 + i];  // Y rows 4t..4t+3, col i (broadcast)
        acc += yc.x * tr[4 * t] + yc.y * tr[4 * t + 1] + yc.z * tr[4 * t + 2] +
               yc.w * tr[4 * t + 3];
      }
      outb[i * 16 + sub] = acc;
    }
  }
}

// Stage 2: ReEig(16) via Jacobi, X3 = Y3^T Lam Y3 with Y3 = U^T w3 (16x4).
// 4 matrices per wave, 128-thread blocks = 8 matrices, all lanes active.
__global__ __launch_bounds__(128, 4) void spd_stage2(
    const float* __restrict__ w3) {
  __shared__ float4 SA[8 * 64];
  __shared__ float2 CS[8 * 8];
  __shared__ float SL[8 * 16];
  __shared__ float4 YL[8 * 16];
  int tid = threadIdx.x;
  int wid = tid >> 6;
  int lane = tid & 63;
  int gl = lane >> 4;
  int sub = lane & 15;
  int g = wid * 4 + gl;
  int b = blockIdx.x * 8 + g;
  float4* SA4g = SA + g * 64;
  float* SAf = (float*)SA4g;
  float2* CSg = CS + g * 8;
  float* SLg = SL + g * 16;
  float* YLf = (float*)(YL + g * 16);

  const float* xb = g_x2 + b * 256;
  float ca[16];
#pragma unroll
  for (int i = 0; i < 16; ++i) ca[i] = xb[i * 16 + sub];
#pragma unroll
  for (int t = 0; t < 4; ++t)
    SA4g[t * 16 + sub] =
        make_float4(ca[4 * t], ca[4 * t + 1], ca[4 * t + 2], ca[4 * t + 3]);
  float ur[16], un[16];
#pragma unroll
  for (int i = 0; i < 16; ++i) ur[i] = (i == sub) ? 1.f : 0.f;
  wsync();

  jacobi_rr<16>(SA4g, CSg, ur, un, sub, 60);  // 4 sweeps (validated minimum)

  const int dAddr = ((sub >> 2) * 16 + sub) * 4 + (sub & 3);
  float lam = fmaxf(SAf[dAddr], EPS_REC);
  SLg[sub] = lam;
  wsync();
#pragma unroll
  for (int t = 0; t < 4; ++t)
    SA4g[t * 16 + sub] =
        make_float4(ur[4 * t], ur[4 * t + 1], ur[4 * t + 2], ur[4 * t + 3]);
  wsync();
  // Y3[sub][j] = sum_i U[i][sub]*w3[i][j]; U[i][sub] = SAf elem(sub,i)
  float y3[4] = {0.f, 0.f, 0.f, 0.f};
  const int rowBase = (sub >> 2) * 64 + (sub & 3);
#pragma unroll
  for (int i = 0; i < 16; ++i) {
    float u = SAf[rowBase + i * 4];
#pragma unroll
    for (int j = 0; j < 4; ++j) y3[j] += u * w3[i * 4 + j];
  }
  ((float4*)YLf)[sub] = make_float4(y3[0], y3[1], y3[2], y3[3]);
  wsync();
  int ii = sub >> 2, jj = sub & 3;
  float acc = 0.f;
#pragma unroll
  for (int r = 0; r < 16; ++r)
    acc += SLg[r] * YLf[r * 4 + ii] * YLf[r * 4 + jj];
  g_x3[b * 16 + sub] = acc;
}

// Stage 3: per-thread 4x4 LogEig in registers, FC(16->2), log_softmax.
__global__ __launch_bounds__(256) void spd_stage3(const float* __restrict__ fcw,
                                                  float* __restrict__ out) {
  int b = blockIdx.x * 256 + threadIdx.x;
  const float* xb = g_x3 + b * 16;
  float a[4][4];
#pragma unroll
  for (int i = 0; i < 4; ++i)
#pragma unroll
    for (int j = 0; j < 4; ++j) a[i][j] = xb[i * 4 + j];
  float vv[4][4];
#pragma unroll
  for (int i = 0; i < 4; ++i)
#pragma unroll
    for (int j = 0; j < 4; ++j) vv[i][j] = (i == j) ? 1.f : 0.f;

  constexpr int P4[6] = {0, 0, 0, 1, 1, 2};
  constexpr int Q4[6] = {1, 2, 3, 2, 3, 3};
  for (int sw = 0; sw < 6; ++sw) {
#pragma unroll
    for (int e = 0; e < 6; ++e) {
      const int p = P4[e], q = Q4[e];
      float c, s;
      rot_cs(a[p][p], a[q][q], a[p][q], c, s);
#pragma unroll
      for (int j = 0; j < 4; ++j) {
        float xx = a[p][j], yy = a[q][j];
        a[p][j] = c * xx - s * yy;
        a[q][j] = s * xx + c * yy;
      }
#pragma unroll
      for (int i = 0; i < 4; ++i) {
        float xx = a[i][p], yy = a[i][q];
        a[i][p] = c * xx - s * yy;
        a[i][q] = s * xx + c * yy;
      }
#pragma unroll
      for (int i = 0; i < 4; ++i) {
        float xx = vv[i][p], yy = vv[i][q];
        vv[i][p] = c * xx - s * yy;
        vv[i][q] = s * xx + c * yy;
      }
    }
  }
  float ll[4];
#pragma unroll
  for (int r = 0; r < 4; ++r) ll[r] = logf(fmaxf(a[r][r], 1e-12f));
  float feat[16];
#pragma unroll
  for (int i = 0; i < 4; ++i)
#pragma unroll
    for (int j = 0; j < 4; ++j) {
      float acc = 0.f;
#pragma unroll
      for (int r = 0; r < 4; ++r) acc += ll[r] * vv[i][r] * vv[j][r];
      feat[i * 4 + j] = acc;
    }
  float z0 = 0.f, z1 = 0.f;
#pragma unroll
  for (int k = 0; k < 16; ++k) {
    z0 += feat[k] * fcw[2 * k + 0];
    z1 += feat[k] * fcw[2 * k + 1];
  }
  float m = fmaxf(z0, z1);
  float lse = logf(expf(z0 - m) + expf(z1 - m));
  out[b * 2 + 0] = z0 - m - lse;
  out[b * 2 + 1] = z1 - m - lse;
#pragma unroll
  for (int k = 0; k < 16; ++k) out[2 * NB + b * 16 + k] = feat[k];
}

extern "C" void kernel_launch(void* const* d_in, const int* in_sizes, int n_in,
                              void* d_out, int out_size, void* d_ws,
                              size_t ws_size, hipStream_t stream) {
  (void)in_sizes;
  (void)n_in;
  (void)out_size;
  (void)d_ws;
  (void)ws_size;
  const float* x = (const float*)d_in[0];
  const float* w1 = (const float*)d_in[1];
  const float* w2 = (const float*)d_in[2];
  const float* w3 = (const float*)d_in[3];
  const float* fcw = (const float*)d_in[4];
  float* out = (float*)d_out;

  spd_stage1<<<(NB + 5) / 6, 128, 0, stream>>>(x, w1, w2);
  spd_stage2<<<NB / 8, 128, 0, stream>>>(w3);
  spd_stage3<<<NB / 256, 256, 0, stream>>>(fcw, out);
}

// Round 10
// 632.184 us; speedup vs baseline: 1.7040x; 1.0141x over previous
//
#include <hip/hip_runtime.h>
#include <math.h>

#define NB 32768
#define EPS_REC 1e-4f

// Inter-stage staging (static device globals: graph-capture safe).
__device__ float g_x2[NB * 256];  // stage-1 output: B x 16 x 16
__device__ float g_x3[NB * 16];   // stage-2 output: B x 4 x 4

// Wave-synchronous "barrier": matrix groups live entirely inside one wave64,
// lanes run in lockstep, same-wave LDS ops complete in order. Only compiler
// reordering must be inhibited -> zero HW cost.
// HISTORY (do not regress):
//  R5: dual-chain ILP (2 matrices/lane-group) -> occupancy halved, +22% time.
//  R6: __launch_bounds__(128,6) -> 85-reg budget -> HBM scratch spills
//      (FETCH 23->407MB), +60%.
//  R8: 3 sweeps -> absmax 1.375 > 0.69 FAIL. 4 sweeps is the minimum
//      (7->0.125, 5->0.25, 4->0.25, 3->1.375; plateau = fp32 noise floor).
//  R9 @ (128,4): 641 us, VGPR=56 arch + ~100 AGPR shuttle -> 3.1 waves/SIMD.
//  R10: (128,3) -> 170-reg budget so the ~90-float live set fits in arch
//       VGPRs (no AGPR shuttle on the critical path), same 3 waves/SIMD.
__device__ __forceinline__ void wsync() {
  asm volatile("" ::: "memory");
  __builtin_amdgcn_wave_barrier();
  asm volatile("" ::: "memory");
}

// Swap values between adjacent lanes (lane ^ 1) via DPP quad_perm [1,0,3,2].
// Pairs (2k,2k+1) are even-aligned so they never cross a quad. VALU-pipe op.
__device__ __forceinline__ float dpp_swap1(float x) {
  int xi = __builtin_bit_cast(int, x);
  int yi = __builtin_amdgcn_update_dpp(xi, xi, 0xB1, 0xF, 0xF, true);
  return __builtin_bit_cast(float, yi);
}

// Tournament (circle-method) slot permutation: content of slot s moves to
// permf(s). Over N-1 rounds with fixed pairing (2k,2k+1) every pair meets
// exactly once.
__host__ __device__ constexpr int permf(int s, int n) {
  return s == 0 ? 0
       : s == 2 ? 1
       : (s & 1) ? (s == n - 1 ? n - 2 : s + 2)
       : s - 2;
}

// Jacobi rotation (c,s) zeroing A[p][q]; G = [[c,s],[-s,c]].
__device__ __forceinline__ void rot_cs(float app, float aqq, float apq,
                                       float& c, float& s) {
  float dd = 0.5f * (app - aqq);
  float q2 = apq * apq;
  float hh = dd * dd + q2 + 1e-30f;
  float h = sqrtf(hh);
  float u = fabsf(dd) + h;
  float gi = rsqrtf(u * u + q2);
  c = u * gi;
  float smag = apq * gi;
  s = (dd >= 0.f) ? -smag : smag;
}

// One Jacobi round, static slot pairing (2k,2k+1), data permuted by permf.
// A in LDS chunk-major: SA4g[t*N + j] = rows 4t..4t+3 of column-slot j.
// U rows ping-pong through register arrays ua -> ub (static indices only).
// Partner-column row-phased values come via DPP, not LDS.
template <int N>
__device__ __forceinline__ void jround(float* SAf, float4* SA4g, float2* CSg,
                                       const float* ua, float* ub, int sub,
                                       int kpair, bool isP, int appAddr,
                                       int aqqAddr, int wcol) {
  constexpr int C = N / 4;
  float2 a01 = *(const float2*)(SAf + appAddr);  // app, apq (adjacent rows)
  float aqq = SAf[aqqAddr];
  float c, s;
  rot_cs(a01.x, aqq, a01.y, c, s);
  if (isP) CSg[kpair] = make_float2(c, s);
  float beta = isP ? -s : s;
  wsync();
  const float4* CS4 = (const float4*)CSg;
  float nn[N];
#pragma unroll
  for (int t = 0; t < C; ++t) {
    float4 cs = CS4[t];            // (c,s) of pairs 2t, 2t+1 (broadcast)
    float4 oc = SA4g[t * N + sub]; // own column, rows 4t..4t+3
    {  // pair 2t: rows p=4t, q=4t+1
      const int p = 4 * t, q = 4 * t + 1;
      float xr = cs.x * oc.x - cs.y * oc.y;
      float yr = cs.y * oc.x + cs.x * oc.y;
      nn[permf(p, N)] = c * xr + beta * dpp_swap1(xr);
      nn[permf(q, N)] = c * yr + beta * dpp_swap1(yr);
      float ux = ua[p], uy = ua[q];
      ub[permf(p, N)] = cs.x * ux - cs.y * uy;
      ub[permf(q, N)] = cs.y * ux + cs.x * uy;
    }
    {  // pair 2t+1: rows p=4t+2, q=4t+3
      const int p = 4 * t + 2, q = 4 * t + 3;
      float xr = cs.z * oc.z - cs.w * oc.w;
      float yr = cs.w * oc.z + cs.z * oc.w;
      nn[permf(p, N)] = c * xr + beta * dpp_swap1(xr);
      nn[permf(q, N)] = c * yr + beta * dpp_swap1(yr);
      float ux = ua[p], uy = ua[q];
      ub[permf(p, N)] = cs.z * ux - cs.w * uy;
      ub[permf(q, N)] = cs.w * ux + cs.z * uy;
    }
  }
  wsync();  // all reads of old columns precede any overwrite (lockstep)
#pragma unroll
  for (int t = 0; t < C; ++t)
    SA4g[t * N + wcol] =
        make_float4(nn[4 * t], nn[4 * t + 1], nn[4 * t + 2], nn[4 * t + 3]);
  wsync();
}

// iters must be even (ping-pong); final U rows end in ur.
template <int N>
__device__ __forceinline__ void jacobi_rr(float4* SA4g, float2* CSg, float* ur,
                                          float* un, int sub, int iters) {
  float* SAf = (float*)SA4g;
  const int kpair = sub >> 1;
  const bool isP = !(sub & 1);
  const int pp = sub & ~1;
  const int qq = pp + 1;
  const int appAddr = ((pp >> 2) * N + pp) * 4 + (pp & 3);
  const int aqqAddr = ((qq >> 2) * N + qq) * 4 + (qq & 3);
  const int wcol = permf(sub, N);
#pragma unroll 1
  for (int it = 0; it < iters; it += 2) {
    jround<N>(SAf, SA4g, CSg, ur, un, sub, kpair, isP, appAddr, aqqAddr, wcol);
    jround<N>(SAf, SA4g, CSg, un, ur, sub, kpair, isP, appAddr, aqqAddr, wcol);
  }
}

// Stage 1: X1 = w1^T X w1 (19 padded to 20), ReEig via Jacobi, then
// X2 = Y^T Lam Y with Y = U^T w2. 3 matrices per wave (lanes 60..63 idle ->
// shared dummy slot 6), 128-thread blocks = 6 matrices.
__global__ __launch_bounds__(128, 3) void spd_stage1(
    const float* __restrict__ x, const float* __restrict__ w1,
    const float* __restrict__ w2) {
  __shared__ float4 SA[7 * 100];  // 6 real groups + 1 dummy, 5 chunks x 20
  __shared__ float2 CS[7 * 10];
  __shared__ float SL[7 * 20];
  int tid = threadIdx.x;
  int wid = tid >> 6;
  int lane = tid & 63;
  int gl = lane / 20;  // 0..3 (3 = idle lanes 60..63)
  int sub = lane - gl * 20;
  bool lane_ok = (gl < 3);
  int g = lane_ok ? (wid * 3 + gl) : 6;
  int b = blockIdx.x * 6 + g;
  bool valid = lane_ok && (b < NB);
  int bm = valid ? b : 0;
  float4* SA4g = SA + g * 100;
  float* SAf = (float*)SA4g;
  float2* CSg = CS + g * 10;
  float* SLg = SL + g * 20;

  // ---- bilinear: Z = w1^T X (col sub), then X1 = Z w1 ----
  const float* xb = x + bm * 361;
  float cx[19];
#pragma unroll
  for (int i = 0; i < 19; ++i) cx[i] = (sub < 19) ? xb[i * 19 + sub] : 0.f;
  float z[20];
  z[19] = 0.f;
#pragma unroll
  for (int i = 0; i < 19; ++i) {
    float acc = 0.f;
#pragma unroll
    for (int r = 0; r < 19; ++r) acc += w1[r * 19 + i] * cx[r];
    z[i] = acc;
  }
#pragma unroll
  for (int t = 0; t < 5; ++t)
    SA4g[t * 20 + sub] =
        make_float4(z[4 * t], z[4 * t + 1], z[4 * t + 2], z[4 * t + 3]);
  wsync();
  float wj[19];
#pragma unroll
  for (int r = 0; r < 19; ++r) wj[r] = (sub < 19) ? w1[r * 19 + sub] : 0.f;
  float a1[20];
#pragma unroll
  for (int i = 0; i < 20; ++i) a1[i] = 0.f;
#pragma unroll
  for (int r = 0; r < 19; ++r) {
    float wr = wj[r];
#pragma unroll
    for (int t = 0; t < 5; ++t) {
      float4 zc = SA4g[t * 20 + r];  // Z rows 4t..4t+3, col r (broadcast)
      a1[4 * t + 0] += zc.x * wr;
      a1[4 * t + 1] += zc.y * wr;
      a1[4 * t + 2] += zc.z * wr;
      a1[4 * t + 3] += zc.w * wr;
    }
  }
  wsync();
  // padded A: col 19 = 0 (diag 0 -> clamped to eps; exact invariant subspace)
#pragma unroll
  for (int t = 0; t < 5; ++t)
    SA4g[t * 20 + sub] =
        make_float4(a1[4 * t], a1[4 * t + 1], a1[4 * t + 2], a1[4 * t + 3]);
  float ur[20], un[20];
#pragma unroll
  for (int i = 0; i < 20; ++i) ur[i] = (i == sub) ? 1.f : 0.f;
  wsync();

  jacobi_rr<20>(SA4g, CSg, ur, un, sub, 76);  // 4 sweeps (validated minimum)

  const int dAddr = ((sub >> 2) * 20 + sub) * 4 + (sub & 3);
  float lam = fmaxf(SAf[dAddr], EPS_REC);
  SLg[sub] = lam;
  wsync();
  // SA col sub <- U row sub  (=> SAf elem(i,j) = U[j][i])
#pragma unroll
  for (int t = 0; t < 5; ++t)
    SA4g[t * 20 + sub] =
        make_float4(ur[4 * t], ur[4 * t + 1], ur[4 * t + 2], ur[4 * t + 3]);
  wsync();
  // Y[r][sub] = sum_{i<19} U[i][r] * w2[i][sub]
  float wj2[19];
#pragma unroll
  for (int i = 0; i < 19; ++i) wj2[i] = (sub < 16) ? w2[i * 16 + sub] : 0.f;
  float y[20];
#pragma unroll
  for (int r = 0; r < 20; ++r) y[r] = 0.f;
#pragma unroll
  for (int i = 0; i < 19; ++i) {
    float wv = wj2[i];
#pragma unroll
    for (int t = 0; t < 5; ++t) {
      float4 u4 = SA4g[t * 20 + i];  // U[i][4t..4t+3] (broadcast)
      y[4 * t + 0] += u4.x * wv;
      y[4 * t + 1] += u4.y * wv;
      y[4 * t + 2] += u4.z * wv;
      y[4 * t + 3] += u4.w * wv;
    }
  }
  wsync();
#pragma unroll
  for (int t = 0; t < 5; ++t)
    SA4g[t * 20 + sub] =
        make_float4(y[4 * t], y[4 * t + 1], y[4 * t + 2], y[4 * t + 3]);
  wsync();
  float tr[20];
#pragma unroll
  for (int r = 0; r < 20; ++r) tr[r] = SLg[r] * y[r];
  if (valid && sub < 16) {
    float* outb = g_x2 + b * 256;
#pragma unroll
    for (int i = 0; i < 16; ++i) {
      float acc = 0.f;
#pragma unroll
      for (int t = 0; t < 5; ++t) {
        float4 yc = SA4g[t * 20 + i];  // Y rows 4t..4t+3, col i (broadcast)
        acc += yc.x * tr[4 * t] + yc.y * tr[4 * t + 1] + yc.z * tr[4 * t + 2] +
               yc.w * tr[4 * t + 3];
      }
      outb[i * 16 + sub] = acc;
    }
  }
}

// Stage 2: ReEig(16) via Jacobi, X3 = Y3^T Lam Y3 with Y3 = U^T w3 (16x4).
// 4 matrices per wave, 128-thread blocks = 8 matrices, all lanes active.
__global__ __launch_bounds__(128, 3) void spd_stage2(
    const float* __restrict__ w3) {
  __shared__ float4 SA[8 * 64];
  __shared__ float2 CS[8 * 8];
  __shared__ float SL[8 * 16];
  __shared__ float4 YL[8 * 16];
  int tid = threadIdx.x;
  int wid = tid >> 6;
  int lane = tid & 63;
  int gl = lane >> 4;
  int sub = lane & 15;
  int g = wid * 4 + gl;
  int b = blockIdx.x * 8 + g;
  float4* SA4g = SA + g * 64;
  float* SAf = (float*)SA4g;
  float2* CSg = CS + g * 8;
  float* SLg = SL + g * 16;
  float* YLf = (float*)(YL + g * 16);

  const float* xb = g_x2 + b * 256;
  float ca[16];
#pragma unroll
  for (int i = 0; i < 16; ++i) ca[i] = xb[i * 16 + sub];
#pragma unroll
  for (int t = 0; t < 4; ++t)
    SA4g[t * 16 + sub] =
        make_float4(ca[4 * t], ca[4 * t + 1], ca[4 * t + 2], ca[4 * t + 3]);
  float ur[16], un[16];
#pragma unroll
  for (int i = 0; i < 16; ++i) ur[i] = (i == sub) ? 1.f : 0.f;
  wsync();

  jacobi_rr<16>(SA4g, CSg, ur, un, sub, 60);  // 4 sweeps (validated minimum)

  const int dAddr = ((sub >> 2) * 16 + sub) * 4 + (sub & 3);
  float lam = fmaxf(SAf[dAddr], EPS_REC);
  SLg[sub] = lam;
  wsync();
#pragma unroll
  for (int t = 0; t < 4; ++t)
    SA4g[t * 16 + sub] =
        make_float4(ur[4 * t], ur[4 * t + 1], ur[4 * t + 2], ur[4 * t + 3]);
  wsync();
  // Y3[sub][j] = sum_i U[i][sub]*w3[i][j]; U[i][sub] = SAf elem(sub,i)
  float y3[4] = {0.f, 0.f, 0.f, 0.f};
  const int rowBase = (sub >> 2) * 64 + (sub & 3);
#pragma unroll
  for (int i = 0; i < 16; ++i) {
    float u = SAf[rowBase + i * 4];
#pragma unroll
    for (int j = 0; j < 4; ++j) y3[j] += u * w3[i * 4 + j];
  }
  ((float4*)YLf)[sub] = make_float4(y3[0], y3[1], y3[2], y3[3]);
  wsync();
  int ii = sub >> 2, jj = sub & 3;
  float acc = 0.f;
#pragma unroll
  for (int r = 0; r < 16; ++r)
    acc += SLg[r] * YLf[r * 4 + ii] * YLf[r * 4 + jj];
  g_x3[b * 16 + sub] = acc;
}

// Stage 3: per-thread 4x4 LogEig in registers, FC(16->2), log_softmax.
__global__ __launch_bounds__(256) void spd_stage3(const float* __restrict__ fcw,
                                                  float* __restrict__ out) {
  int b = blockIdx.x * 256 + threadIdx.x;
  const float* xb = g_x3 + b * 16;
  float a[4][4];
#pragma unroll
  for (int i = 0; i < 4; ++i)
#pragma unroll
    for (int j = 0; j < 4; ++j) a[i][j] = xb[i * 4 + j];
  float vv[4][4];
#pragma unroll
  for (int i = 0; i < 4; ++i)
#pragma unroll
    for (int j = 0; j < 4; ++j) vv[i][j] = (i == j) ? 1.f : 0.f;

  constexpr int P4[6] = {0, 0, 0, 1, 1, 2};
  constexpr int Q4[6] = {1, 2, 3, 2, 3, 3};
  for (int sw = 0; sw < 6; ++sw) {
#pragma unroll
    for (int e = 0; e < 6; ++e) {
      const int p = P4[e], q = Q4[e];
      float c, s;
      rot_cs(a[p][p], a[q][q], a[p][q], c, s);
#pragma unroll
      for (int j = 0; j < 4; ++j) {
        float xx = a[p][j], yy = a[q][j];
        a[p][j] = c * xx - s * yy;
        a[q][j] = s * xx + c * yy;
      }
#pragma unroll
      for (int i = 0; i < 4; ++i) {
        float xx = a[i][p], yy = a[i][q];
        a[i][p] = c * xx - s * yy;
        a[i][q] = s * xx + c * yy;
      }
#pragma unroll
      for (int i = 0; i < 4; ++i) {
        float xx = vv[i][p], yy = vv[i][q];
        vv[i][p] = c * xx - s * yy;
        vv[i][q] = s * xx + c * yy;
      }
    }
  }
  float ll[4];
#pragma unroll
  for (int r = 0; r < 4; ++r) ll[r] = logf(fmaxf(a[r][r], 1e-12f));
  float feat[16];
#pragma unroll
  for (int i = 0; i < 4; ++i)
#pragma unroll
    for (int j = 0; j < 4; ++j) {
      float acc = 0.f;
#pragma unroll
      for (int r = 0; r < 4; ++r) acc += ll[r] * vv[i][r] * vv[j][r];
      feat[i * 4 + j] = acc;
    }
  float z0 = 0.f, z1 = 0.f;
#pragma unroll
  for (int k = 0; k < 16; ++k) {
    z0 += feat[k] * fcw[2 * k + 0];
    z1 += feat[k] * fcw[2 * k + 1];
  }
  float m = fmaxf(z0, z1);
  float lse = logf(expf(z0 - m) + expf(z1 - m));
  out[b * 2 + 0] = z0 - m - lse;
  out[b * 2 + 1] = z1 - m - lse;
#pragma unroll
  for (int k = 0; k < 16; ++k) out[2 * NB + b * 16 + k] = feat[k];
}

extern "C" void kernel_launch(void* const* d_in, const int* in_sizes, int n_in,
                              void* d_out, int out_size, void* d_ws,
                              size_t ws_size, hipStream_t stream) {
  (void)in_sizes;
  (void)n_in;
  (void)out_size;
  (void)d_ws;
  (void)ws_size;
  const float* x = (const float*)d_in[0];
  const float* w1 = (const float*)d_in[1];
  const float* w2 = (const float*)d_in[2];
  const float* w3 = (const float*)d_in[3];
  const float* fcw = (const float*)d_in[4];
  float* out = (float*)d_out;

  spd_stage1<<<(NB + 5) / 6, 128, 0, stream>>>(x, w1, w2);
  spd_stage2<<<NB / 8, 128, 0, stream>>>(w3);
  spd_stage3<<<NB / 256, 256, 0, stream>>>(fcw, out);
}